// Round 5
// baseline (464.665 us; speedup 1.0000x reference)
//
#include <hip/hip_runtime.h>
#include <math.h>

#define B_N 8192
#define K_N 256
#define D_N 768
#define BM 32
#define KC 32
#define NKB (D_N / KC)

static constexpr float ALPHA_C = 0.2f;
static constexpr float BETA_C  = 0.3f;
static constexpr float EPS_C   = 1e-8f;
static constexpr float NEG_INF_C = -10000.0f;
static constexpr float INV_WTEMP = 20.0f;   // 1/0.05

__device__ __forceinline__ float rdlane(float x, int l) {
    return __int_as_float(__builtin_amdgcn_readlane(__float_as_int(x), l));
}

// ---------------------------------------------------------------------------
// K0: normalize centroid rows, write TRANSPOSED CnT[768][256] into ws
// ---------------------------------------------------------------------------
__global__ __launch_bounds__(256) void k_centroid_prep(
        const float* __restrict__ centroid, float* __restrict__ cnt) {
    int c = blockIdx.x, t = threadIdx.x;
    const float* p = centroid + c * D_N;
    float v0 = p[t], v1 = p[t + 256], v2 = p[t + 512];
    float s = v0 * v0 + v1 * v1 + v2 * v2;
    #pragma unroll
    for (int o = 32; o >= 1; o >>= 1) s += __shfl_xor(s, o);
    __shared__ float red[4];
    __shared__ float sinv;
    if ((t & 63) == 0) red[t >> 6] = s;
    __syncthreads();
    if (t == 0)
        sinv = 1.0f / fmaxf(sqrtf(red[0] + red[1] + red[2] + red[3]), EPS_C);
    __syncthreads();
    float inv = sinv;
    cnt[(t)       * K_N + c] = v0 * inv;
    cnt[(t + 256) * K_N + c] = v1 * inv;
    cnt[(t + 512) * K_N + c] = v2 * inv;
}

// ---------------------------------------------------------------------------
// K1: fused intra GEMM + row-norm + top-2 + centroid gather.
// block = 32 rows x 256 cols, 256 threads (4 waves), 1 block/CU.
// A-operand: each wave loads its 8 dp rows direct to regs (1 float4/lane/kb);
//   wave-uniform a-values broadcast via v_readlane -> SGPR-operand FMAs (no DS).
// B-operand: cnt tile [KC][256] in LDS, prefetched to regs before inner loop.
// Per-CU per k: DS = 4 waves x 1 b128 = 48 cyc < VALU = 40 instr x 2 = 80 cyc.
// ---------------------------------------------------------------------------
__device__ __forceinline__ bool top_better(float v, int iv, float w, int iw) {
    return (v > w) || ((v == w) && (iv < iw));
}

__global__ __launch_bounds__(256) void k_intra(
        const float* __restrict__ dp, const float* __restrict__ cnt,
        const float* __restrict__ centroid,
        float* __restrict__ out_intra, unsigned char* __restrict__ cid_g,
        float* __restrict__ dp_centroid, float* __restrict__ hard_negative) {
    __shared__ float ct[KC][K_N];        // 32 KB
    int t = threadIdx.x;
    int l = t & 63;                       // lane
    int ty = t >> 6;                      // wave id
    int row0 = blockIdx.x * BM;
    int c0 = l * 4;                       // this lane's 4 centroid cols
    int r0 = ty * 8;                      // this wave's 8 rows
    int myrow = row0 + r0 + (l >> 3);     // dp row this lane stages
    int kq = l & 7;                       // k-quad within kb
    int sk = t >> 6;                      // ct staging base k (= ty)

    float acc[8][4];
    #pragma unroll
    for (int r = 0; r < 8; ++r)
        #pragma unroll
        for (int c = 0; c < 4; ++c) acc[r][c] = 0.f;

    // prologue: stage ct for kb=0, load dp quad for kb=0
    float4 sreg[8];
    #pragma unroll
    for (int u = 0; u < 8; ++u)
        sreg[u] = *(const float4*)&cnt[(size_t)(sk + 4 * u) * K_N + c0];
    float4 dcur = *(const float4*)&dp[(size_t)myrow * D_N + kq * 4];
    #pragma unroll
    for (int u = 0; u < 8; ++u)
        *(float4*)&ct[sk + 4 * u][c0] = sreg[u];
    __syncthreads();

    float ss = 0.f;
    for (int kbi = 0; kbi < NKB; ++kbi) {
        // prefetch next kb (clamped; unused on last iter)
        int kbn = (kbi + 1 < NKB) ? (kbi + 1) * KC : 0;
        #pragma unroll
        for (int u = 0; u < 8; ++u)
            sreg[u] = *(const float4*)&cnt[(size_t)(kbn + sk + 4 * u) * K_N + c0];
        float4 dnxt = *(const float4*)&dp[(size_t)myrow * D_N + kbn + kq * 4];

        ss += dcur.x * dcur.x + dcur.y * dcur.y + dcur.z * dcur.z + dcur.w * dcur.w;

        // inner: 32 k-steps on current ct + dcur
        #pragma unroll
        for (int k = 0; k < KC; ++k) {
            float4 b4 = *(float4*)&ct[k][c0];
            float comp = ((k & 3) == 0) ? dcur.x : ((k & 3) == 1) ? dcur.y
                       : ((k & 3) == 2) ? dcur.z : dcur.w;
            #pragma unroll
            for (int r = 0; r < 8; ++r) {
                float a = rdlane(comp, (r << 3) | (k >> 2));
                acc[r][0] += a * b4.x;
                acc[r][1] += a * b4.y;
                acc[r][2] += a * b4.z;
                acc[r][3] += a * b4.w;
            }
        }
        __syncthreads();          // all waves done reading ct
        if (kbi + 1 < NKB) {
            #pragma unroll
            for (int u = 0; u < 8; ++u)
                *(float4*)&ct[sk + 4 * u][c0] = sreg[u];
        }
        dcur = dnxt;
        __syncthreads();          // ct(next) visible
    }

    // row 1/norm: sum ss over the 8 lanes sharing a row (offsets 1,2,4)
    #pragma unroll
    for (int o = 1; o <= 4; o <<= 1) ss += __shfl_xor(ss, o);
    float rinv = 1.0f / fmaxf(sqrtf(ss), EPS_C);

    // per row: scale+store intra, wave top-2, cid + gather
    #pragma unroll 1
    for (int r = 0; r < 8; ++r) {
        int row = row0 + r0 + r;
        float rv = rdlane(rinv, r << 3);
        float4 o;
        o.x = acc[r][0] * rv; o.y = acc[r][1] * rv;
        o.z = acc[r][2] * rv; o.w = acc[r][3] * rv;
        *(float4*)&out_intra[(size_t)row * K_N + c0] = o;

        float m1 = o.x, m2 = -1e30f;
        int i1 = c0, i2 = K_N;
        { float v = o.y; int id = c0 + 1;
          if (v > m1) { m2 = m1; i2 = i1; m1 = v; i1 = id; } else if (v > m2) { m2 = v; i2 = id; } }
        { float v = o.z; int id = c0 + 2;
          if (v > m1) { m2 = m1; i2 = i1; m1 = v; i1 = id; } else if (v > m2) { m2 = v; i2 = id; } }
        { float v = o.w; int id = c0 + 3;
          if (v > m1) { m2 = m1; i2 = i1; m1 = v; i1 = id; } else if (v > m2) { m2 = v; i2 = id; } }
        #pragma unroll
        for (int off = 32; off >= 1; off >>= 1) {
            float om1 = __shfl_xor(m1, off);
            int   oi1 = __shfl_xor(i1, off);
            float om2 = __shfl_xor(m2, off);
            int   oi2 = __shfl_xor(i2, off);
            if (top_better(om1, oi1, m1, i1)) {
                if (top_better(m1, i1, om2, oi2)) { m2 = m1; i2 = i1; }
                else                              { m2 = om2; i2 = oi2; }
                m1 = om1; i1 = oi1;
            } else if (top_better(om1, oi1, m2, i2)) {
                m2 = om1; i2 = oi1;
            }
        }
        if (l == 0) cid_g[row] = (unsigned char)i1;

        const float4* s1 = (const float4*)(centroid + (size_t)i1 * D_N);
        const float4* s2 = (const float4*)(centroid + (size_t)i2 * D_N);
        float4* d1 = (float4*)(dp_centroid   + (size_t)row * D_N);
        float4* d2 = (float4*)(hard_negative + (size_t)row * D_N);
        #pragma unroll
        for (int u = 0; u < 3; ++u) {
            d1[l + 64 * u] = s1[l + 64 * u];
            d2[l + 64 * u] = s2[l + 64 * u];
        }
    }
}

// ---------------------------------------------------------------------------
// K3: fused per-row pass over batch_cos_sim — ALL-SCALAR, zero row-LDS.
// Thread t owns elements {t+256u}, lane-consecutive -> every load/store is a
// 256B contiguous wave access; row lives in 32 VGPRs across phases.
// No DS wall (was ~160us), occupancy 8 blocks/CU (VGPR-bound).
// ---------------------------------------------------------------------------
__global__ __launch_bounds__(256) void k_row(
        const float* __restrict__ bcs, const unsigned char* __restrict__ cid_g,
        float* __restrict__ dp_cluster, float* __restrict__ weights,
        double* __restrict__ accd) {
    int i = blockIdx.x;
    int t = threadIdx.x;
    __shared__ float red[4];
    __shared__ float posb;

    const float* src = bcs + (size_t)i * B_N;
    float v[32];
    float mx = -3.0e38f;
    #pragma unroll
    for (int u = 0; u < 32; ++u) {
        int j = t + 256 * u;
        v[u] = src[j];
        if (j == i) posb = v[u];
        mx = fmaxf(mx, (j == i) ? NEG_INF_C : v[u]);
    }
    #pragma unroll
    for (int o = 32; o >= 1; o >>= 1) mx = fmaxf(mx, __shfl_xor(mx, o));
    if ((t & 63) == 0) red[t >> 6] = mx;
    __syncthreads();                        // red + posb visible
    mx = fmaxf(fmaxf(red[0], red[1]), fmaxf(red[2], red[3]));
    float pos = posb;
    unsigned myc = (unsigned)cid_g[i];
    __syncthreads();                        // red consumed before reuse

    float fn = 0.f, se = 0.f;
    float* dcrow = dp_cluster + (size_t)i * B_N;
    #pragma unroll
    for (int u = 0; u < 32; ++u) {
        int j = t + 256 * u;
        bool same = ((unsigned)cid_g[j] == myc) & (j != i);
        float delta = same ? (v[u] - pos) : 0.f;
        fn += fmaxf(delta + ALPHA_C, 0.f) + fmaxf(-delta - BETA_C, 0.f);
        dcrow[j] = same ? 1.0f : 0.f;
        float e = __expf(((j == i) ? NEG_INF_C : v[u]) - mx);
        se += e;
        v[u] = e;
    }

    // sum(exp) reduce
    #pragma unroll
    for (int o = 32; o >= 1; o >>= 1) se += __shfl_xor(se, o);
    if ((t & 63) == 0) red[t >> 6] = se;
    __syncthreads();
    se = red[0] + red[1] + red[2] + red[3];
    float inv = INV_WTEMP / se;

    float* wrow = weights + (size_t)i * B_N;
    #pragma unroll
    for (int u = 0; u < 32; ++u)
        wrow[t + 256 * u] = v[u] * inv;

    // fn_loss partial
    #pragma unroll
    for (int o = 32; o >= 1; o >>= 1) fn += __shfl_xor(fn, o);
    __syncthreads();                        // red (se) consumed
    if ((t & 63) == 0) red[t >> 6] = fn;
    __syncthreads();
    if (t == 0) atomicAdd(accd, (double)(red[0] + red[1] + red[2] + red[3]));
}

// ---------------------------------------------------------------------------
// K4: finalize fn_loss = acc / B^2  (stream order provides visibility)
// ---------------------------------------------------------------------------
__global__ void k_final(const double* __restrict__ acc, float* __restrict__ out) {
    out[0] = (float)(acc[0] / ((double)B_N * (double)B_N));
}

// ---------------------------------------------------------------------------
extern "C" void kernel_launch(void* const* d_in, const int* in_sizes, int n_in,
                              void* d_out, int out_size, void* d_ws, size_t ws_size,
                              hipStream_t stream) {
    const float* dp       = (const float*)d_in[0];
    const float* centroid = (const float*)d_in[1];
    const float* bcs      = (const float*)d_in[2];
    float* out = (float*)d_out;

    float* intra       = out;                       // [8192,256]
    float* dp_cluster  = out + 2097152;             // [8192,8192]
    float* dp_centroid = out + 69206016;            // [8192,768]
    float* hard_neg    = out + 75497472;            // [8192,768]
    float* fn_out      = out + 81788928;             // [1]
    float* weights     = out + 81788929;            // [8192,8192]

    char* ws = (char*)d_ws;
    double*        acc = (double*)ws;                             // 8 B
    float*         cnt = (float*)(ws + 256);                      // 768*256*4
    unsigned char* cid = (unsigned char*)(ws + 256 + 786432);     // 8192

    hipMemsetAsync(ws, 0, 16, stream);
    k_centroid_prep<<<K_N, 256, 0, stream>>>(centroid, cnt);
    k_intra<<<B_N / BM, 256, 0, stream>>>(dp, cnt, centroid, intra, cid,
                                          dp_centroid, hard_neg);
    k_row<<<B_N, 256, 0, stream>>>(bcs, cid, dp_cluster, weights, acc);
    k_final<<<1, 1, 0, stream>>>(acc, fn_out);
}

// Round 6
// 344.757 us; speedup vs baseline: 1.3478x; 1.3478x over previous
//
#include <hip/hip_runtime.h>
#include <math.h>

#define B_N 8192
#define K_N 256
#define D_N 768
#define BM 32
#define KC 32
#define NKB (D_N / KC)

static constexpr float ALPHA_C = 0.2f;
static constexpr float BETA_C  = 0.3f;
static constexpr float EPS_C   = 1e-8f;
static constexpr float NEG_INF_C = -10000.0f;
static constexpr float INV_WTEMP = 20.0f;   // 1/0.05

__device__ __forceinline__ float rdlane(float x, int l) {
    return __int_as_float(__builtin_amdgcn_readlane(__float_as_int(x), l));
}

// ---------------------------------------------------------------------------
// K0: normalize centroid rows, write TRANSPOSED CnT[768][256] into ws
// ---------------------------------------------------------------------------
__global__ __launch_bounds__(256) void k_centroid_prep(
        const float* __restrict__ centroid, float* __restrict__ cnt) {
    int c = blockIdx.x, t = threadIdx.x;
    const float* p = centroid + c * D_N;
    float v0 = p[t], v1 = p[t + 256], v2 = p[t + 512];
    float s = v0 * v0 + v1 * v1 + v2 * v2;
    #pragma unroll
    for (int o = 32; o >= 1; o >>= 1) s += __shfl_xor(s, o);
    __shared__ float red[4];
    __shared__ float sinv;
    if ((t & 63) == 0) red[t >> 6] = s;
    __syncthreads();
    if (t == 0)
        sinv = 1.0f / fmaxf(sqrtf(red[0] + red[1] + red[2] + red[3]), EPS_C);
    __syncthreads();
    float inv = sinv;
    cnt[(t)       * K_N + c] = v0 * inv;
    cnt[(t + 256) * K_N + c] = v1 * inv;
    cnt[(t + 512) * K_N + c] = v2 * inv;
}

// ---------------------------------------------------------------------------
// K1: fused intra GEMM + row-norm + top-2 + centroid gather (R5 readlane kept).
// block = 32 rows x 256 cols, 256 threads (4 waves), 1 block/CU.
// A-operand: regs + v_readlane broadcast (no DS). B: ct LDS, 1 b128/k/wave.
// Model: per-CU DS 15us, per-SIMD VALU ~25us.
// ---------------------------------------------------------------------------
__device__ __forceinline__ bool top_better(float v, int iv, float w, int iw) {
    return (v > w) || ((v == w) && (iv < iw));
}

__global__ __launch_bounds__(256) void k_intra(
        const float* __restrict__ dp, const float* __restrict__ cnt,
        const float* __restrict__ centroid,
        float* __restrict__ out_intra, unsigned char* __restrict__ cid_g,
        float* __restrict__ dp_centroid, float* __restrict__ hard_negative) {
    __shared__ float ct[KC][K_N];        // 32 KB
    int t = threadIdx.x;
    int l = t & 63;                       // lane
    int ty = t >> 6;                      // wave id
    int row0 = blockIdx.x * BM;
    int c0 = l * 4;                       // this lane's 4 centroid cols
    int r0 = ty * 8;                      // this wave's 8 rows
    int myrow = row0 + r0 + (l >> 3);     // dp row this lane stages
    int kq = l & 7;                       // k-quad within kb
    int sk = ty;                          // ct staging base k

    float acc[8][4];
    #pragma unroll
    for (int r = 0; r < 8; ++r)
        #pragma unroll
        for (int c = 0; c < 4; ++c) acc[r][c] = 0.f;

    // prologue: stage ct for kb=0, load dp quad for kb=0
    float4 sreg[8];
    #pragma unroll
    for (int u = 0; u < 8; ++u)
        sreg[u] = *(const float4*)&cnt[(size_t)(sk + 4 * u) * K_N + c0];
    float4 dcur = *(const float4*)&dp[(size_t)myrow * D_N + kq * 4];
    #pragma unroll
    for (int u = 0; u < 8; ++u)
        *(float4*)&ct[sk + 4 * u][c0] = sreg[u];
    __syncthreads();

    float ss = 0.f;
    for (int kbi = 0; kbi < NKB; ++kbi) {
        int kbn = (kbi + 1 < NKB) ? (kbi + 1) * KC : 0;
        #pragma unroll
        for (int u = 0; u < 8; ++u)
            sreg[u] = *(const float4*)&cnt[(size_t)(kbn + sk + 4 * u) * K_N + c0];
        float4 dnxt = *(const float4*)&dp[(size_t)myrow * D_N + kbn + kq * 4];

        ss += dcur.x * dcur.x + dcur.y * dcur.y + dcur.z * dcur.z + dcur.w * dcur.w;

        #pragma unroll
        for (int k = 0; k < KC; ++k) {
            float4 b4 = *(float4*)&ct[k][c0];
            float comp = ((k & 3) == 0) ? dcur.x : ((k & 3) == 1) ? dcur.y
                       : ((k & 3) == 2) ? dcur.z : dcur.w;
            #pragma unroll
            for (int r = 0; r < 8; ++r) {
                float a = rdlane(comp, (r << 3) | (k >> 2));
                acc[r][0] += a * b4.x;
                acc[r][1] += a * b4.y;
                acc[r][2] += a * b4.z;
                acc[r][3] += a * b4.w;
            }
        }
        __syncthreads();
        if (kbi + 1 < NKB) {
            #pragma unroll
            for (int u = 0; u < 8; ++u)
                *(float4*)&ct[sk + 4 * u][c0] = sreg[u];
        }
        dcur = dnxt;
        __syncthreads();
    }

    // row norm: sum ss over the 8 lanes sharing a row
    #pragma unroll
    for (int o = 1; o <= 4; o <<= 1) ss += __shfl_xor(ss, o);
    float rinv = 1.0f / fmaxf(sqrtf(ss), EPS_C);

    #pragma unroll 1
    for (int r = 0; r < 8; ++r) {
        int row = row0 + r0 + r;
        float rv = rdlane(rinv, r << 3);
        float4 o;
        o.x = acc[r][0] * rv; o.y = acc[r][1] * rv;
        o.z = acc[r][2] * rv; o.w = acc[r][3] * rv;
        *(float4*)&out_intra[(size_t)row * K_N + c0] = o;

        float m1 = o.x, m2 = -1e30f;
        int i1 = c0, i2 = K_N;
        { float v = o.y; int id = c0 + 1;
          if (v > m1) { m2 = m1; i2 = i1; m1 = v; i1 = id; } else if (v > m2) { m2 = v; i2 = id; } }
        { float v = o.z; int id = c0 + 2;
          if (v > m1) { m2 = m1; i2 = i1; m1 = v; i1 = id; } else if (v > m2) { m2 = v; i2 = id; } }
        { float v = o.w; int id = c0 + 3;
          if (v > m1) { m2 = m1; i2 = i1; m1 = v; i1 = id; } else if (v > m2) { m2 = v; i2 = id; } }
        #pragma unroll
        for (int off = 32; off >= 1; off >>= 1) {
            float om1 = __shfl_xor(m1, off);
            int   oi1 = __shfl_xor(i1, off);
            float om2 = __shfl_xor(m2, off);
            int   oi2 = __shfl_xor(i2, off);
            if (top_better(om1, oi1, m1, i1)) {
                if (top_better(m1, i1, om2, oi2)) { m2 = m1; i2 = i1; }
                else                              { m2 = om2; i2 = oi2; }
                m1 = om1; i1 = oi1;
            } else if (top_better(om1, oi1, m2, i2)) {
                m2 = om1; i2 = oi1;
            }
        }
        if (l == 0) cid_g[row] = (unsigned char)i1;

        const float4* s1 = (const float4*)(centroid + (size_t)i1 * D_N);
        const float4* s2 = (const float4*)(centroid + (size_t)i2 * D_N);
        float4* d1 = (float4*)(dp_centroid   + (size_t)row * D_N);
        float4* d2 = (float4*)(hard_negative + (size_t)row * D_N);
        #pragma unroll
        for (int u = 0; u < 3; ++u) {
            d1[l + 64 * u] = s1[l + 64 * u];
            d2[l + 64 * u] = s2[l + 64 * u];
        }
    }
}

// ---------------------------------------------------------------------------
// K3: fused per-row pass over batch_cos_sim — EXACT round-4 version (known-good).
// LDS = 32KB row + red; cid read from global (L2-hot); float4 loads/stores.
// ---------------------------------------------------------------------------
__global__ __launch_bounds__(256) void k_row(
        const float* __restrict__ bcs, const unsigned char* __restrict__ cid_g,
        float* __restrict__ dp_cluster, float* __restrict__ weights,
        double* __restrict__ accd) {
    int i = blockIdx.x;
    int t = threadIdx.x;
    __shared__ float4 row4[B_N / 4];           // 32 KB
    __shared__ float  red[4];
    float* row = (float*)row4;
    const unsigned* cidw = (const unsigned*)cid_g;   // global, stays L2-hot

    // stage row + masked max
    const float4* src = (const float4*)(bcs + (size_t)i * B_N);
    float mx = -3.0e38f;
    #pragma unroll
    for (int u = 0; u < 8; ++u) {
        int f4 = t + 256 * u;
        float4 v = src[f4];
        row4[f4] = v;
        int j0 = f4 * 4;
        float a = (j0     == i) ? NEG_INF_C : v.x;
        float b = (j0 + 1 == i) ? NEG_INF_C : v.y;
        float c = (j0 + 2 == i) ? NEG_INF_C : v.z;
        float d = (j0 + 3 == i) ? NEG_INF_C : v.w;
        mx = fmaxf(mx, fmaxf(fmaxf(a, b), fmaxf(c, d)));
    }
    __syncthreads();     // row visible
    #pragma unroll
    for (int o = 32; o >= 1; o >>= 1) mx = fmaxf(mx, __shfl_xor(mx, o));
    if ((t & 63) == 0) red[t >> 6] = mx;
    __syncthreads();
    mx = fmaxf(fmaxf(red[0], red[1]), fmaxf(red[2], red[3]));

    float pos = row[i];
    unsigned myc = (unsigned)cid_g[i];
    __syncthreads();     // pos read, red consumed, before row overwrite

    float fn = 0.f, se = 0.f;
    float* dcrow = dp_cluster + (size_t)i * B_N;
    #pragma unroll
    for (int r = 0; r < 8; ++r) {
        int f4 = t + 256 * r;
        int j0 = f4 * 4;
        unsigned cw = cidw[f4];
        float4 v = row4[f4];
        float4 e, dc;
        {
            bool same = ((cw & 255u) == myc) & (j0 != i);
            float delta = same ? (v.x - pos) : 0.f;
            fn += fmaxf(delta + ALPHA_C, 0.f) + fmaxf(-delta - BETA_C, 0.f);
            dc.x = same ? 1.0f : 0.f;
            e.x = __expf(((j0 == i) ? NEG_INF_C : v.x) - mx);
        }
        {
            bool same = (((cw >> 8) & 255u) == myc) & (j0 + 1 != i);
            float delta = same ? (v.y - pos) : 0.f;
            fn += fmaxf(delta + ALPHA_C, 0.f) + fmaxf(-delta - BETA_C, 0.f);
            dc.y = same ? 1.0f : 0.f;
            e.y = __expf(((j0 + 1 == i) ? NEG_INF_C : v.y) - mx);
        }
        {
            bool same = (((cw >> 16) & 255u) == myc) & (j0 + 2 != i);
            float delta = same ? (v.z - pos) : 0.f;
            fn += fmaxf(delta + ALPHA_C, 0.f) + fmaxf(-delta - BETA_C, 0.f);
            dc.z = same ? 1.0f : 0.f;
            e.z = __expf(((j0 + 2 == i) ? NEG_INF_C : v.z) - mx);
        }
        {
            bool same = (((cw >> 24) & 255u) == myc) & (j0 + 3 != i);
            float delta = same ? (v.w - pos) : 0.f;
            fn += fmaxf(delta + ALPHA_C, 0.f) + fmaxf(-delta - BETA_C, 0.f);
            dc.w = same ? 1.0f : 0.f;
            e.w = __expf(((j0 + 3 == i) ? NEG_INF_C : v.w) - mx);
        }
        se += e.x + e.y + e.z + e.w;
        row4[f4] = e;                       // overwrite with exp values
        ((float4*)dcrow)[f4] = dc;
    }

    // sum(exp) reduce
    #pragma unroll
    for (int o = 32; o >= 1; o >>= 1) se += __shfl_xor(se, o);
    if ((t & 63) == 0) red[t >> 6] = se;
    __syncthreads();
    se = red[0] + red[1] + red[2] + red[3];
    float inv = INV_WTEMP / se;

    // weights: base has odd float offset -> lane-consecutive scalar stores
    float* wrow = weights + (size_t)i * B_N;
    #pragma unroll
    for (int r = 0; r < 32; ++r) {
        int j = t + 256 * r;
        wrow[j] = row[j] * inv;
    }

    // fn_loss partial
    #pragma unroll
    for (int o = 32; o >= 1; o >>= 1) fn += __shfl_xor(fn, o);
    __syncthreads();     // done reading red (se)
    if ((t & 63) == 0) red[t >> 6] = fn;
    __syncthreads();
    if (t == 0) atomicAdd(accd, (double)(red[0] + red[1] + red[2] + red[3]));
}

// ---------------------------------------------------------------------------
// K4: finalize fn_loss = acc / B^2  (stream order provides visibility)
// ---------------------------------------------------------------------------
__global__ void k_final(const double* __restrict__ acc, float* __restrict__ out) {
    out[0] = (float)(acc[0] / ((double)B_N * (double)B_N));
}

// ---------------------------------------------------------------------------
extern "C" void kernel_launch(void* const* d_in, const int* in_sizes, int n_in,
                              void* d_out, int out_size, void* d_ws, size_t ws_size,
                              hipStream_t stream) {
    const float* dp       = (const float*)d_in[0];
    const float* centroid = (const float*)d_in[1];
    const float* bcs      = (const float*)d_in[2];
    float* out = (float*)d_out;

    float* intra       = out;                       // [8192,256]
    float* dp_cluster  = out + 2097152;             // [8192,8192]
    float* dp_centroid = out + 69206016;            // [8192,768]
    float* hard_neg    = out + 75497472;            // [8192,768]
    float* fn_out      = out + 81788928;            // [1]
    float* weights     = out + 81788929;            // [8192,8192]

    char* ws = (char*)d_ws;
    double*        acc = (double*)ws;                             // 8 B
    float*         cnt = (float*)(ws + 256);                      // 768*256*4
    unsigned char* cid = (unsigned char*)(ws + 256 + 786432);     // 8192

    hipMemsetAsync(ws, 0, 16, stream);
    k_centroid_prep<<<K_N, 256, 0, stream>>>(centroid, cnt);
    k_intra<<<B_N / BM, 256, 0, stream>>>(dp, cnt, centroid, intra, cid,
                                          dp_centroid, hard_neg);
    k_row<<<B_N, 256, 0, stream>>>(bcs, cid, dp_cluster, weights, acc);
    k_final<<<1, 1, 0, stream>>>(acc, fn_out);
}

// Round 7
// 249.984 us; speedup vs baseline: 1.8588x; 1.3791x over previous
//
#include <hip/hip_runtime.h>
#include <math.h>

#define B_N 8192
#define K_N 256
#define D_N 768
#define BM 32
#define KC 32

static constexpr float ALPHA_C = 0.2f;
static constexpr float BETA_C  = 0.3f;
static constexpr float EPS_C   = 1e-8f;
static constexpr float NEG_INF_C = -10000.0f;
static constexpr float INV_WTEMP = 20.0f;   // 1/0.05

// ---------------------------------------------------------------------------
// K0: normalize centroid rows, write TRANSPOSED CnT[768][256] into ws
// ---------------------------------------------------------------------------
__global__ __launch_bounds__(256) void k_centroid_prep(
        const float* __restrict__ centroid, float* __restrict__ cnt) {
    int c = blockIdx.x, t = threadIdx.x;
    const float* p = centroid + c * D_N;
    float v0 = p[t], v1 = p[t + 256], v2 = p[t + 512];
    float s = v0 * v0 + v1 * v1 + v2 * v2;
    #pragma unroll
    for (int o = 32; o >= 1; o >>= 1) s += __shfl_xor(s, o);
    __shared__ float red[4];
    __shared__ float sinv;
    if ((t & 63) == 0) red[t >> 6] = s;
    __syncthreads();
    if (t == 0)
        sinv = 1.0f / fmaxf(sqrtf(red[0] + red[1] + red[2] + red[3]), EPS_C);
    __syncthreads();
    float inv = sinv;
    cnt[(t)       * K_N + c] = v0 * inv;
    cnt[(t + 256) * K_N + c] = v1 * inv;
    cnt[(t + 512) * K_N + c] = v2 * inv;
}

// ---------------------------------------------------------------------------
// K1: fused intra GEMM + row-norm + top-2 + centroid gather — EXACT round-4
// version (measured-good: ~52us inside the 242.5 total).
// ---------------------------------------------------------------------------
__device__ __forceinline__ bool top_better(float v, int iv, float w, int iw) {
    return (v > w) || ((v == w) && (iv < iw));
}

__global__ __launch_bounds__(256) void k_intra(
        const float* __restrict__ dp, const float* __restrict__ cnt,
        const float* __restrict__ centroid,
        float* __restrict__ out_intra, unsigned char* __restrict__ cid_g,
        float* __restrict__ dp_centroid, float* __restrict__ hard_negative) {
    __shared__ float ct[KC][K_N];        // 32 KB
    __shared__ float dpt[KC][BM + 4];    // 4.6 KB, row stride 144 B (16B-aligned)
    __shared__ float sqp[BM][8];
    __shared__ float rn[BM];
    int t = threadIdx.x;
    int row0 = blockIdx.x * BM;
    int tx = t & 63, ty = t >> 6;
    int c0 = tx * 4;
    int r0 = ty * 8;
    int sr = t >> 3, skq = t & 7;

    float acc[8][4];
    #pragma unroll
    for (int r = 0; r < 8; ++r)
        #pragma unroll
        for (int c = 0; c < 4; ++c) acc[r][c] = 0.f;
    float ss = 0.f;

    for (int kb = 0; kb < D_N; kb += KC) {
        __syncthreads();
        #pragma unroll
        for (int u = 0; u < 8; ++u) {
            int f4 = t + 256 * u;                 // 0..2047
            int k = f4 >> 6, c4 = (f4 & 63) << 2;
            *(float4*)&ct[k][c4] = *(const float4*)&cnt[(size_t)(kb + k) * K_N + c4];
        }
        {
            float4 v = *(const float4*)&dp[(size_t)(row0 + sr) * D_N + kb + skq * 4];
            ss += v.x * v.x + v.y * v.y + v.z * v.z + v.w * v.w;
            dpt[skq * 4 + 0][sr] = v.x;
            dpt[skq * 4 + 1][sr] = v.y;
            dpt[skq * 4 + 2][sr] = v.z;
            dpt[skq * 4 + 3][sr] = v.w;
        }
        __syncthreads();
        #pragma unroll
        for (int k = 0; k < KC; ++k) {
            float4 b4 = *(float4*)&ct[k][c0];
            float4 a0 = *(float4*)&dpt[k][r0];
            float4 a1 = *(float4*)&dpt[k][r0 + 4];
            float a[8] = {a0.x, a0.y, a0.z, a0.w, a1.x, a1.y, a1.z, a1.w};
            float b[4] = {b4.x, b4.y, b4.z, b4.w};
            #pragma unroll
            for (int r = 0; r < 8; ++r)
                #pragma unroll
                for (int c = 0; c < 4; ++c)
                    acc[r][c] += a[r] * b[c];
        }
    }

    // row norms
    sqp[sr][skq] = ss;
    __syncthreads();
    if (t < BM) {
        float s = 0.f;
        #pragma unroll
        for (int j = 0; j < 8; ++j) s += sqp[t][j];
        rn[t] = 1.0f / fmaxf(sqrtf(s), EPS_C);
    }
    __syncthreads();

    // per row: scale+store intra, wave top-2, cid + gather
    #pragma unroll 1
    for (int r = 0; r < 8; ++r) {
        int row = row0 + r0 + r;
        float rv = rn[r0 + r];
        float4 o;
        o.x = acc[r][0] * rv; o.y = acc[r][1] * rv;
        o.z = acc[r][2] * rv; o.w = acc[r][3] * rv;
        *(float4*)&out_intra[(size_t)row * K_N + c0] = o;

        float m1 = o.x, m2 = -1e30f;
        int i1 = c0, i2 = K_N;
        { float v = o.y; int id = c0 + 1;
          if (v > m1) { m2 = m1; i2 = i1; m1 = v; i1 = id; } else if (v > m2) { m2 = v; i2 = id; } }
        { float v = o.z; int id = c0 + 2;
          if (v > m1) { m2 = m1; i2 = i1; m1 = v; i1 = id; } else if (v > m2) { m2 = v; i2 = id; } }
        { float v = o.w; int id = c0 + 3;
          if (v > m1) { m2 = m1; i2 = i1; m1 = v; i1 = id; } else if (v > m2) { m2 = v; i2 = id; } }
        #pragma unroll
        for (int off = 32; off >= 1; off >>= 1) {
            float om1 = __shfl_xor(m1, off);
            int   oi1 = __shfl_xor(i1, off);
            float om2 = __shfl_xor(m2, off);
            int   oi2 = __shfl_xor(i2, off);
            if (top_better(om1, oi1, m1, i1)) {
                if (top_better(m1, i1, om2, oi2)) { m2 = m1; i2 = i1; }
                else                              { m2 = om2; i2 = oi2; }
                m1 = om1; i1 = oi1;
            } else if (top_better(om1, oi1, m2, i2)) {
                m2 = om1; i2 = oi1;
            }
        }
        if (tx == 0) cid_g[row] = (unsigned char)i1;

        const float4* s1 = (const float4*)(centroid + (size_t)i1 * D_N);
        const float4* s2 = (const float4*)(centroid + (size_t)i2 * D_N);
        float4* d1 = (float4*)(dp_centroid   + (size_t)row * D_N);
        float4* d2 = (float4*)(hard_negative + (size_t)row * D_N);
        #pragma unroll
        for (int u = 0; u < 3; ++u) {
            d1[tx + 64 * u] = s1[tx + 64 * u];
            d2[tx + 64 * u] = s2[tx + 64 * u];
        }
    }
}

// ---------------------------------------------------------------------------
// K3 v2: reg-resident row pass. float4 loads (as R4), packed-uint cid loads
// (as R4), but NO 32KB LDS row: pos via broadcast scalar, exp kept in the
// same 8 float4 regs for the weights pass. LDS = 20 B -> ~8 blocks/CU.
// ---------------------------------------------------------------------------
__global__ __launch_bounds__(256) void k_row(
        const float* __restrict__ bcs, const unsigned char* __restrict__ cid_g,
        float* __restrict__ dp_cluster, float* __restrict__ weights,
        double* __restrict__ accd) {
    int i = blockIdx.x;
    int t = threadIdx.x;
    __shared__ float red[4];
    __shared__ float posb;
    const unsigned* cidw = (const unsigned*)cid_g;   // global, L2-hot

    // load row into 8 float4 regs + masked max
    const float4* src = (const float4*)(bcs + (size_t)i * B_N);
    float4 v[8];
    float mx = -3.0e38f;
    #pragma unroll
    for (int u = 0; u < 8; ++u) {
        int f4 = t + 256 * u;
        v[u] = src[f4];
        int j0 = f4 * 4;
        float a = (j0     == i) ? NEG_INF_C : v[u].x;
        float b = (j0 + 1 == i) ? NEG_INF_C : v[u].y;
        float c = (j0 + 2 == i) ? NEG_INF_C : v[u].z;
        float d = (j0 + 3 == i) ? NEG_INF_C : v[u].w;
        mx = fmaxf(mx, fmaxf(fmaxf(a, b), fmaxf(c, d)));
    }
    // owner thread publishes pos (static unroll, no runtime reg indexing)
    {
        int ti = (i >> 2) & 255;        // owning thread of float4 #(i/4)
        int ui = i >> 10;               // which u slot
        int q  = i & 3;
        if (t == ti) {
            float pe = 0.f;
            #pragma unroll
            for (int u = 0; u < 8; ++u)
                if (u == ui)
                    pe = (q == 0) ? v[u].x : (q == 1) ? v[u].y
                       : (q == 2) ? v[u].z : v[u].w;
            posb = pe;
        }
    }
    #pragma unroll
    for (int o = 32; o >= 1; o >>= 1) mx = fmaxf(mx, __shfl_xor(mx, o));
    if ((t & 63) == 0) red[t >> 6] = mx;
    __syncthreads();                    // red + posb visible
    mx = fmaxf(fmaxf(red[0], red[1]), fmaxf(red[2], red[3]));
    float pos = posb;
    unsigned myc = (unsigned)cid_g[i];
    __syncthreads();                    // red consumed before reuse

    float fn = 0.f, se = 0.f;
    float* dcrow = dp_cluster + (size_t)i * B_N;
    #pragma unroll
    for (int u = 0; u < 8; ++u) {
        int f4 = t + 256 * u;
        int j0 = f4 * 4;
        unsigned cw = cidw[f4];
        float4 w = v[u], e, dc;
        {
            bool same = ((cw & 255u) == myc) & (j0 != i);
            float delta = same ? (w.x - pos) : 0.f;
            fn += fmaxf(delta + ALPHA_C, 0.f) + fmaxf(-delta - BETA_C, 0.f);
            dc.x = same ? 1.0f : 0.f;
            e.x = __expf(((j0 == i) ? NEG_INF_C : w.x) - mx);
        }
        {
            bool same = (((cw >> 8) & 255u) == myc) & (j0 + 1 != i);
            float delta = same ? (w.y - pos) : 0.f;
            fn += fmaxf(delta + ALPHA_C, 0.f) + fmaxf(-delta - BETA_C, 0.f);
            dc.y = same ? 1.0f : 0.f;
            e.y = __expf(((j0 + 1 == i) ? NEG_INF_C : w.y) - mx);
        }
        {
            bool same = (((cw >> 16) & 255u) == myc) & (j0 + 2 != i);
            float delta = same ? (w.z - pos) : 0.f;
            fn += fmaxf(delta + ALPHA_C, 0.f) + fmaxf(-delta - BETA_C, 0.f);
            dc.z = same ? 1.0f : 0.f;
            e.z = __expf(((j0 + 2 == i) ? NEG_INF_C : w.z) - mx);
        }
        {
            bool same = (((cw >> 24) & 255u) == myc) & (j0 + 3 != i);
            float delta = same ? (w.w - pos) : 0.f;
            fn += fmaxf(delta + ALPHA_C, 0.f) + fmaxf(-delta - BETA_C, 0.f);
            dc.w = same ? 1.0f : 0.f;
            e.w = __expf(((j0 + 3 == i) ? NEG_INF_C : w.w) - mx);
        }
        se += e.x + e.y + e.z + e.w;
        v[u] = e;                           // exp stays in regs
        ((float4*)dcrow)[f4] = dc;
    }

    // sum(exp) reduce
    #pragma unroll
    for (int o = 32; o >= 1; o >>= 1) se += __shfl_xor(se, o);
    if ((t & 63) == 0) red[t >> 6] = se;
    __syncthreads();
    se = red[0] + red[1] + red[2] + red[3];
    float inv = INV_WTEMP / se;

    // weights: base has odd float offset -> lane-consecutive scalar stores
    float* wrow = weights + (size_t)i * B_N;
    #pragma unroll
    for (int u = 0; u < 8; ++u) {
        int j0 = (t + 256 * u) * 4;
        wrow[j0]     = v[u].x * inv;
        wrow[j0 + 1] = v[u].y * inv;
        wrow[j0 + 2] = v[u].z * inv;
        wrow[j0 + 3] = v[u].w * inv;
    }

    // fn_loss partial
    #pragma unroll
    for (int o = 32; o >= 1; o >>= 1) fn += __shfl_xor(fn, o);
    __syncthreads();                    // red (se) consumed
    if ((t & 63) == 0) red[t >> 6] = fn;
    __syncthreads();
    if (t == 0) atomicAdd(accd, (double)(red[0] + red[1] + red[2] + red[3]));
}

// ---------------------------------------------------------------------------
// K4: finalize fn_loss = acc / B^2  (stream order provides visibility)
// ---------------------------------------------------------------------------
__global__ void k_final(const double* __restrict__ acc, float* __restrict__ out) {
    out[0] = (float)(acc[0] / ((double)B_N * (double)B_N));
}

// ---------------------------------------------------------------------------
extern "C" void kernel_launch(void* const* d_in, const int* in_sizes, int n_in,
                              void* d_out, int out_size, void* d_ws, size_t ws_size,
                              hipStream_t stream) {
    const float* dp       = (const float*)d_in[0];
    const float* centroid = (const float*)d_in[1];
    const float* bcs      = (const float*)d_in[2];
    float* out = (float*)d_out;

    float* intra       = out;                       // [8192,256]
    float* dp_cluster  = out + 2097152;             // [8192,8192]
    float* dp_centroid = out + 69206016;            // [8192,768]
    float* hard_neg    = out + 75497472;            // [8192,768]
    float* fn_out      = out + 81788928;            // [1]
    float* weights     = out + 81788929;            // [8192,8192]

    char* ws = (char*)d_ws;
    double*        acc = (double*)ws;                             // 8 B
    float*         cnt = (float*)(ws + 256);                      // 768*256*4
    unsigned char* cid = (unsigned char*)(ws + 256 + 786432);     // 8192

    hipMemsetAsync(ws, 0, 16, stream);
    k_centroid_prep<<<K_N, 256, 0, stream>>>(centroid, cnt);
    k_intra<<<B_N / BM, 256, 0, stream>>>(dp, cnt, centroid, intra, cid,
                                          dp_centroid, hard_neg);
    k_row<<<B_N, 256, 0, stream>>>(bcs, cid, dp_cluster, weights, acc);
    k_final<<<1, 1, 0, stream>>>(acc, fn_out);
}

// Round 8
// 241.400 us; speedup vs baseline: 1.9249x; 1.0356x over previous
//
#include <hip/hip_runtime.h>
#include <math.h>

#define B_N 8192
#define K_N 256
#define D_N 768
#define BM 32
#define KC 32

static constexpr float ALPHA_C = 0.2f;
static constexpr float BETA_C  = 0.3f;
static constexpr float EPS_C   = 1e-8f;
static constexpr float NEG_INF_C = -10000.0f;
static constexpr float INV_WTEMP = 20.0f;   // 1/0.05

// ---------------------------------------------------------------------------
// K0: normalize centroid rows, write TRANSPOSED CnT[768][256] into ws
// ---------------------------------------------------------------------------
__global__ __launch_bounds__(256) void k_centroid_prep(
        const float* __restrict__ centroid, float* __restrict__ cnt) {
    int c = blockIdx.x, t = threadIdx.x;
    const float* p = centroid + c * D_N;
    float v0 = p[t], v1 = p[t + 256], v2 = p[t + 512];
    float s = v0 * v0 + v1 * v1 + v2 * v2;
    #pragma unroll
    for (int o = 32; o >= 1; o >>= 1) s += __shfl_xor(s, o);
    __shared__ float red[4];
    __shared__ float sinv;
    if ((t & 63) == 0) red[t >> 6] = s;
    __syncthreads();
    if (t == 0)
        sinv = 1.0f / fmaxf(sqrtf(red[0] + red[1] + red[2] + red[3]), EPS_C);
    __syncthreads();
    float inv = sinv;
    cnt[(t)       * K_N + c] = v0 * inv;
    cnt[(t + 256) * K_N + c] = v1 * inv;
    cnt[(t + 512) * K_N + c] = v2 * inv;
}

// ---------------------------------------------------------------------------
// K1: fused intra GEMM + row-norm + top-2 + centroid gather — EXACT round-4
// version (measured-good). Untouched this round.
// ---------------------------------------------------------------------------
__device__ __forceinline__ bool top_better(float v, int iv, float w, int iw) {
    return (v > w) || ((v == w) && (iv < iw));
}

__global__ __launch_bounds__(256) void k_intra(
        const float* __restrict__ dp, const float* __restrict__ cnt,
        const float* __restrict__ centroid,
        float* __restrict__ out_intra, unsigned char* __restrict__ cid_g,
        float* __restrict__ dp_centroid, float* __restrict__ hard_negative) {
    __shared__ float ct[KC][K_N];        // 32 KB
    __shared__ float dpt[KC][BM + 4];    // 4.6 KB, row stride 144 B (16B-aligned)
    __shared__ float sqp[BM][8];
    __shared__ float rn[BM];
    int t = threadIdx.x;
    int row0 = blockIdx.x * BM;
    int tx = t & 63, ty = t >> 6;
    int c0 = tx * 4;
    int r0 = ty * 8;
    int sr = t >> 3, skq = t & 7;

    float acc[8][4];
    #pragma unroll
    for (int r = 0; r < 8; ++r)
        #pragma unroll
        for (int c = 0; c < 4; ++c) acc[r][c] = 0.f;
    float ss = 0.f;

    for (int kb = 0; kb < D_N; kb += KC) {
        __syncthreads();
        #pragma unroll
        for (int u = 0; u < 8; ++u) {
            int f4 = t + 256 * u;                 // 0..2047
            int k = f4 >> 6, c4 = (f4 & 63) << 2;
            *(float4*)&ct[k][c4] = *(const float4*)&cnt[(size_t)(kb + k) * K_N + c4];
        }
        {
            float4 v = *(const float4*)&dp[(size_t)(row0 + sr) * D_N + kb + skq * 4];
            ss += v.x * v.x + v.y * v.y + v.z * v.z + v.w * v.w;
            dpt[skq * 4 + 0][sr] = v.x;
            dpt[skq * 4 + 1][sr] = v.y;
            dpt[skq * 4 + 2][sr] = v.z;
            dpt[skq * 4 + 3][sr] = v.w;
        }
        __syncthreads();
        #pragma unroll
        for (int k = 0; k < KC; ++k) {
            float4 b4 = *(float4*)&ct[k][c0];
            float4 a0 = *(float4*)&dpt[k][r0];
            float4 a1 = *(float4*)&dpt[k][r0 + 4];
            float a[8] = {a0.x, a0.y, a0.z, a0.w, a1.x, a1.y, a1.z, a1.w};
            float b[4] = {b4.x, b4.y, b4.z, b4.w};
            #pragma unroll
            for (int r = 0; r < 8; ++r)
                #pragma unroll
                for (int c = 0; c < 4; ++c)
                    acc[r][c] += a[r] * b[c];
        }
    }

    // row norms
    sqp[sr][skq] = ss;
    __syncthreads();
    if (t < BM) {
        float s = 0.f;
        #pragma unroll
        for (int j = 0; j < 8; ++j) s += sqp[t][j];
        rn[t] = 1.0f / fmaxf(sqrtf(s), EPS_C);
    }
    __syncthreads();

    // per row: scale+store intra, wave top-2, cid + gather
    #pragma unroll 1
    for (int r = 0; r < 8; ++r) {
        int row = row0 + r0 + r;
        float rv = rn[r0 + r];
        float4 o;
        o.x = acc[r][0] * rv; o.y = acc[r][1] * rv;
        o.z = acc[r][2] * rv; o.w = acc[r][3] * rv;
        *(float4*)&out_intra[(size_t)row * K_N + c0] = o;

        float m1 = o.x, m2 = -1e30f;
        int i1 = c0, i2 = K_N;
        { float v = o.y; int id = c0 + 1;
          if (v > m1) { m2 = m1; i2 = i1; m1 = v; i1 = id; } else if (v > m2) { m2 = v; i2 = id; } }
        { float v = o.z; int id = c0 + 2;
          if (v > m1) { m2 = m1; i2 = i1; m1 = v; i1 = id; } else if (v > m2) { m2 = v; i2 = id; } }
        { float v = o.w; int id = c0 + 3;
          if (v > m1) { m2 = m1; i2 = i1; m1 = v; i1 = id; } else if (v > m2) { m2 = v; i2 = id; } }
        #pragma unroll
        for (int off = 32; off >= 1; off >>= 1) {
            float om1 = __shfl_xor(m1, off);
            int   oi1 = __shfl_xor(i1, off);
            float om2 = __shfl_xor(m2, off);
            int   oi2 = __shfl_xor(i2, off);
            if (top_better(om1, oi1, m1, i1)) {
                if (top_better(m1, i1, om2, oi2)) { m2 = m1; i2 = i1; }
                else                              { m2 = om2; i2 = oi2; }
                m1 = om1; i1 = oi1;
            } else if (top_better(om1, oi1, m2, i2)) {
                m2 = om1; i2 = oi1;
            }
        }
        if (tx == 0) cid_g[row] = (unsigned char)i1;

        const float4* s1 = (const float4*)(centroid + (size_t)i1 * D_N);
        const float4* s2 = (const float4*)(centroid + (size_t)i2 * D_N);
        float4* d1 = (float4*)(dp_centroid   + (size_t)row * D_N);
        float4* d2 = (float4*)(hard_negative + (size_t)row * D_N);
        #pragma unroll
        for (int u = 0; u < 3; ++u) {
            d1[tx + 64 * u] = s1[tx + 64 * u];
            d2[tx + 64 * u] = s2[tx + 64 * u];
        }
    }
}

// ---------------------------------------------------------------------------
// K3 v3: reg-resident row pass, NO max-subtraction (softmax shift-invariant;
// inputs ~N(0,1), exp<=e^5 fp32-safe, diag exp(-1e4)=0), cid prefetched,
// per-block float partial instead of same-address double atomic.
// 2 barriers (was 4). LDS ~40 B.
// ---------------------------------------------------------------------------
__global__ __launch_bounds__(256) void k_row(
        const float* __restrict__ bcs, const unsigned char* __restrict__ cid_g,
        float* __restrict__ dp_cluster, float* __restrict__ weights,
        float* __restrict__ partials) {
    int i = blockIdx.x;
    int t = threadIdx.x;
    __shared__ float red_se[4], red_fn[4];
    __shared__ float posb;
    const unsigned* cidw = (const unsigned*)cid_g;   // global, L2-hot

    // load row + cid words into regs
    const float4* src = (const float4*)(bcs + (size_t)i * B_N);
    float4 v[8];
    unsigned cw[8];
    #pragma unroll
    for (int u = 0; u < 8; ++u) {
        int f4 = t + 256 * u;
        v[u] = src[f4];
        cw[u] = cidw[f4];
    }
    // owner thread publishes pos (static unroll, no runtime reg indexing)
    {
        int ti = (i >> 2) & 255;        // owning thread of float4 #(i/4)
        int ui = i >> 10;               // which u slot
        int q  = i & 3;
        if (t == ti) {
            float pe = 0.f;
            #pragma unroll
            for (int u = 0; u < 8; ++u)
                if (u == ui)
                    pe = (q == 0) ? v[u].x : (q == 1) ? v[u].y
                       : (q == 2) ? v[u].z : v[u].w;
            posb = pe;
        }
    }
    __syncthreads();                    // posb visible
    float pos = posb;
    unsigned myc = (unsigned)cid_g[i];

    float fn = 0.f, se = 0.f;
    float* dcrow = dp_cluster + (size_t)i * B_N;
    #pragma unroll
    for (int u = 0; u < 8; ++u) {
        int f4 = t + 256 * u;
        int j0 = f4 * 4;
        unsigned c = cw[u];
        float4 w = v[u], e, dc;
        {
            bool same = ((c & 255u) == myc) & (j0 != i);
            float delta = same ? (w.x - pos) : 0.f;
            fn += fmaxf(delta + ALPHA_C, 0.f) + fmaxf(-delta - BETA_C, 0.f);
            dc.x = same ? 1.0f : 0.f;
            e.x = __expf((j0 == i) ? NEG_INF_C : w.x);
        }
        {
            bool same = (((c >> 8) & 255u) == myc) & (j0 + 1 != i);
            float delta = same ? (w.y - pos) : 0.f;
            fn += fmaxf(delta + ALPHA_C, 0.f) + fmaxf(-delta - BETA_C, 0.f);
            dc.y = same ? 1.0f : 0.f;
            e.y = __expf((j0 + 1 == i) ? NEG_INF_C : w.y);
        }
        {
            bool same = (((c >> 16) & 255u) == myc) & (j0 + 2 != i);
            float delta = same ? (w.z - pos) : 0.f;
            fn += fmaxf(delta + ALPHA_C, 0.f) + fmaxf(-delta - BETA_C, 0.f);
            dc.z = same ? 1.0f : 0.f;
            e.z = __expf((j0 + 2 == i) ? NEG_INF_C : w.z);
        }
        {
            bool same = (((c >> 24) & 255u) == myc) & (j0 + 3 != i);
            float delta = same ? (w.w - pos) : 0.f;
            fn += fmaxf(delta + ALPHA_C, 0.f) + fmaxf(-delta - BETA_C, 0.f);
            dc.w = same ? 1.0f : 0.f;
            e.w = __expf((j0 + 3 == i) ? NEG_INF_C : w.w);
        }
        se += e.x + e.y + e.z + e.w;
        v[u] = e;                           // exp stays in regs
        ((float4*)dcrow)[f4] = dc;
    }

    // joint se + fn reduce (one barrier)
    #pragma unroll
    for (int o = 32; o >= 1; o >>= 1) {
        se += __shfl_xor(se, o);
        fn += __shfl_xor(fn, o);
    }
    if ((t & 63) == 0) { red_se[t >> 6] = se; red_fn[t >> 6] = fn; }
    __syncthreads();
    se = red_se[0] + red_se[1] + red_se[2] + red_se[3];
    float inv = INV_WTEMP / se;

    // weights: base has odd float offset -> scalar stores (lane-16B-stride)
    float* wrow = weights + (size_t)i * B_N;
    #pragma unroll
    for (int u = 0; u < 8; ++u) {
        int j0 = (t + 256 * u) * 4;
        wrow[j0]     = v[u].x * inv;
        wrow[j0 + 1] = v[u].y * inv;
        wrow[j0 + 2] = v[u].z * inv;
        wrow[j0 + 3] = v[u].w * inv;
    }

    if (t == 0)
        partials[i] = red_fn[0] + red_fn[1] + red_fn[2] + red_fn[3];
}

// ---------------------------------------------------------------------------
// K4: reduce 8192 per-block partials -> fn_loss (fixed order, deterministic)
// ---------------------------------------------------------------------------
__global__ __launch_bounds__(256) void k_final(
        const float* __restrict__ partials, float* __restrict__ out) {
    int t = threadIdx.x;
    __shared__ double red[4];
    double s = 0.0;
    #pragma unroll
    for (int u = 0; u < 32; ++u) s += (double)partials[t + 256 * u];
    #pragma unroll
    for (int o = 32; o >= 1; o >>= 1) s += __shfl_xor(s, o);
    if ((t & 63) == 0) red[t >> 6] = s;
    __syncthreads();
    if (t == 0)
        out[0] = (float)((red[0] + red[1] + red[2] + red[3])
                         / ((double)B_N * (double)B_N));
}

// ---------------------------------------------------------------------------
extern "C" void kernel_launch(void* const* d_in, const int* in_sizes, int n_in,
                              void* d_out, int out_size, void* d_ws, size_t ws_size,
                              hipStream_t stream) {
    const float* dp       = (const float*)d_in[0];
    const float* centroid = (const float*)d_in[1];
    const float* bcs      = (const float*)d_in[2];
    float* out = (float*)d_out;

    float* intra       = out;                       // [8192,256]
    float* dp_cluster  = out + 2097152;             // [8192,8192]
    float* dp_centroid = out + 69206016;            // [8192,768]
    float* hard_neg    = out + 75497472;            // [8192,768]
    float* fn_out      = out + 81788928;            // [1]
    float* weights     = out + 81788929;            // [8192,8192]

    char* ws = (char*)d_ws;
    float*         cnt      = (float*)(ws + 256);                      // 768*256*4
    unsigned char* cid      = (unsigned char*)(ws + 256 + 786432);     // 8192
    float*         partials = (float*)(ws + 256 + 786432 + 8192);      // 32768

    k_centroid_prep<<<K_N, 256, 0, stream>>>(centroid, cnt);
    k_intra<<<B_N / BM, 256, 0, stream>>>(dp, cnt, centroid, intra, cid,
                                          dp_centroid, hard_neg);
    k_row<<<B_N, 256, 0, stream>>>(bcs, cid, dp_cluster, weights, partials);
    k_final<<<1, 256, 0, stream>>>(partials, fn_out);
}